// Round 2
// baseline (1127.249 us; speedup 1.0000x reference)
//
#include <hip/hip_runtime.h>
#include <hip/hip_bf16.h>
#include <hip/hip_fp16.h>

#define N_NODES 100000
#define N_EDGES 3200000
#define NFEAT 512
#define HDIM 64
#define NCLASS 40
#define N_LAYERS 4
#define NEG_SLOPE 0.2f

__device__ __forceinline__ float leaky(float x) {
    return x >= 0.f ? x : NEG_SLOPE * x;
}

// ---------------- CSR build ----------------

__global__ void histo_kernel(const int* __restrict__ ei, int* __restrict__ deg) {
    int stride = gridDim.x * blockDim.x;
    for (int e = blockIdx.x * blockDim.x + threadIdx.x; e < N_EDGES; e += stride) {
        int d = ei[N_EDGES + e];
        atomicAdd(&deg[d], 1);
    }
}

__global__ __launch_bounds__(1024) void scan_block_kernel(const int* __restrict__ deg,
                                                          int* __restrict__ rp,
                                                          int* __restrict__ bsum, int n) {
    __shared__ int s[1024];
    int t = threadIdx.x;
    int i = blockIdx.x * 1024 + t;
    int v = (i < n) ? deg[i] : 0;
    s[t] = v;
    __syncthreads();
    for (int off = 1; off < 1024; off <<= 1) {
        int x = (t >= off) ? s[t - off] : 0;
        __syncthreads();
        s[t] += x;
        __syncthreads();
    }
    if (i < n) rp[i] = s[t] - v;        // exclusive
    if (t == 1023) bsum[blockIdx.x] = s[t];
}

__global__ __launch_bounds__(1024) void scan_partials_kernel(int* __restrict__ bsum, int nb) {
    __shared__ int s[1024];
    int t = threadIdx.x;
    int v = (t < nb) ? bsum[t] : 0;
    s[t] = v;
    __syncthreads();
    for (int off = 1; off < 1024; off <<= 1) {
        int x = (t >= off) ? s[t - off] : 0;
        __syncthreads();
        s[t] += x;
        __syncthreads();
    }
    if (t < nb) bsum[t] = s[t] - v;     // exclusive
}

__global__ void fixup_kernel(int* __restrict__ rp, const int* __restrict__ bsum,
                             int* __restrict__ cursor, int n) {
    int i = blockIdx.x * blockDim.x + threadIdx.x;
    if (i < n) {
        int v = rp[i] + bsum[i >> 10];
        rp[i] = v;
        cursor[i] = v;
    }
    if (i == n) rp[n] = N_EDGES;
}

__global__ void fill_kernel(const int* __restrict__ ei, int* __restrict__ cursor,
                            int* __restrict__ col) {
    int stride = gridDim.x * blockDim.x;
    for (int e = blockIdx.x * blockDim.x + threadIdx.x; e < N_EDGES; e += stride) {
        int s = ei[e];
        int d = ei[N_EDGES + e];
        int p = atomicAdd(&cursor[d], 1);
        col[p] = s;
    }
}

// ---------------- GEMM: C[M x 64] = A[M x K] @ B[K x 64] (+ bias) ----------------
// block 256 = 16x16 threads, tile 64x64, micro-tile 4x4, BK=16

__global__ __launch_bounds__(256) void gemm_rt(const float* __restrict__ A,
                                               const float* __restrict__ B,
                                               const float* __restrict__ bias,
                                               float* __restrict__ C, int M, int K) {
    __shared__ float As[16][65];  // [k][m], padded
    __shared__ float Bs[16][64];  // [k][n]
    int t = threadIdx.x;
    int tx = t & 15;   // col group
    int ty = t >> 4;   // row group
    int row0 = blockIdx.x * 64;
    float acc[4][4] = {};
    for (int kt = 0; kt < K; kt += 16) {
        // A tile: 64 rows x 16 k
        {
            int r = t >> 2;            // 0..63
            int kk = (t & 3) << 2;     // 0,4,8,12
            int gr = row0 + r;
            float4 v = make_float4(0.f, 0.f, 0.f, 0.f);
            if (gr < M) v = *(const float4*)&A[(size_t)gr * K + kt + kk];
            As[kk + 0][r] = v.x;
            As[kk + 1][r] = v.y;
            As[kk + 2][r] = v.z;
            As[kk + 3][r] = v.w;
        }
        // B tile: 16 k x 64 n
        {
            int kk = t >> 4;           // 0..15
            int n0 = (t & 15) << 2;
            float4 v = *(const float4*)&B[(size_t)(kt + kk) * 64 + n0];
            *(float4*)&Bs[kk][n0] = v;
        }
        __syncthreads();
#pragma unroll
        for (int kk = 0; kk < 16; ++kk) {
            float a0 = As[kk][ty * 4 + 0];
            float a1 = As[kk][ty * 4 + 1];
            float a2 = As[kk][ty * 4 + 2];
            float a3 = As[kk][ty * 4 + 3];
            float4 b = *(float4*)&Bs[kk][tx * 4];
            acc[0][0] += a0 * b.x; acc[0][1] += a0 * b.y; acc[0][2] += a0 * b.z; acc[0][3] += a0 * b.w;
            acc[1][0] += a1 * b.x; acc[1][1] += a1 * b.y; acc[1][2] += a1 * b.z; acc[1][3] += a1 * b.w;
            acc[2][0] += a2 * b.x; acc[2][1] += a2 * b.y; acc[2][2] += a2 * b.z; acc[2][3] += a2 * b.w;
            acc[3][0] += a3 * b.x; acc[3][1] += a3 * b.y; acc[3][2] += a3 * b.z; acc[3][3] += a3 * b.w;
        }
        __syncthreads();
    }
#pragma unroll
    for (int i = 0; i < 4; ++i) {
        int gr = row0 + ty * 4 + i;
        if (gr < M) {
#pragma unroll
            for (int j = 0; j < 4; ++j) {
                int n = tx * 4 + j;
                float bv = bias ? bias[n] : 0.f;
                C[(size_t)gr * 64 + n] = acc[i][j] + bv;
            }
        }
    }
}

// ---------------- attention dot products + fp16 copy ----------------

__global__ __launch_bounds__(256) void att_dots_kernel(const float* __restrict__ h2,
                                                       const float* __restrict__ att_s,
                                                       const float* __restrict__ att_d,
                                                       float* __restrict__ as_,
                                                       float* __restrict__ ad_,
                                                       __half* __restrict__ h2h) {
    int wid = blockIdx.x * (blockDim.x >> 6) + (threadIdx.x >> 6);
    int lane = threadIdx.x & 63;
    if (wid >= N_NODES) return;
    float v = h2[(size_t)wid * 64 + lane];
    h2h[(size_t)wid * 64 + lane] = __float2half(v);
    float ps = v * att_s[lane];
    float pd = v * att_d[lane];
#pragma unroll
    for (int off = 32; off; off >>= 1) {
        ps += __shfl_xor(ps, off);
        pd += __shfl_xor(pd, off);
    }
    if (lane == 0) {
        as_[wid] = ps;
        ad_[wid] = pd;
    }
}

// ---------------- GAT aggregation: wave per dst node, lane = feature ----------------

__global__ __launch_bounds__(256) void gat_aggregate(const int* __restrict__ rp,
                                                     const int* __restrict__ col,
                                                     const __half* __restrict__ h2h,
                                                     const float* __restrict__ h2f,
                                                     const float* __restrict__ as_,
                                                     const float* __restrict__ ad_,
                                                     const float* __restrict__ bias,
                                                     float* __restrict__ h /* in/out */) {
    int wid = blockIdx.x * (blockDim.x >> 6) + (threadIdx.x >> 6);
    int lane = threadIdx.x & 63;
    if (wid >= N_NODES) return;
    int beg = rp[wid];
    int end = rp[wid + 1];
    float adv = ad_[wid];
    float e_self = leaky(as_[wid] + adv);

    // phase 1: max over incoming edges + self
    float mloc = e_self;
    for (int j = beg + lane; j < end; j += 64) {
        mloc = fmaxf(mloc, leaky(as_[col[j]] + adv));
    }
#pragma unroll
    for (int off = 32; off; off >>= 1) mloc = fmaxf(mloc, __shfl_xor(mloc, off));
    float m = mloc;

    // phase 2: weighted accumulation
    float w_self = __expf(e_self - m);
    float acc = w_self * h2f[(size_t)wid * 64 + lane];
    float wpart = 0.f;
    for (int j0 = beg; j0 < end; j0 += 64) {
        int rem = end - j0;
        int cnt = rem < 64 ? rem : 64;
        int s = 0;
        float w = 0.f;
        if (lane < cnt) {
            s = col[j0 + lane];
            w = __expf(leaky(as_[s] + adv) - m);
        }
        wpart += w;
        int j = 0;
        for (; j + 4 <= cnt; j += 4) {
            float w0 = __shfl(w, j), w1 = __shfl(w, j + 1);
            float w2 = __shfl(w, j + 2), w3 = __shfl(w, j + 3);
            int s0 = __shfl(s, j), s1 = __shfl(s, j + 1);
            int s2 = __shfl(s, j + 2), s3 = __shfl(s, j + 3);
            float v0 = __half2float(h2h[(size_t)s0 * 64 + lane]);
            float v1 = __half2float(h2h[(size_t)s1 * 64 + lane]);
            float v2 = __half2float(h2h[(size_t)s2 * 64 + lane]);
            float v3 = __half2float(h2h[(size_t)s3 * 64 + lane]);
            acc += w0 * v0;
            acc += w1 * v1;
            acc += w2 * v2;
            acc += w3 * v3;
        }
        for (; j < cnt; ++j) {
            float wj = __shfl(w, j);
            int sj = __shfl(s, j);
            acc += wj * __half2float(h2h[(size_t)sj * 64 + lane]);
        }
    }
#pragma unroll
    for (int off = 32; off; off >>= 1) wpart += __shfl_xor(wpart, off);
    float denom = wpart + w_self;

    float o = acc / denom + bias[lane];
    float e = (o > 0.f) ? o : expm1f(o);
    size_t idx = (size_t)wid * 64 + lane;
    h[idx] = h[idx] + e;   // residual, in place (own row only)
}

// ---------------- output GEMM: out[N x 40] = h[N x 64] @ W[64 x 40] + b ----------------

__global__ __launch_bounds__(256) void out_gemm(const float* __restrict__ h,
                                                const float* __restrict__ W,
                                                const float* __restrict__ b,
                                                float* __restrict__ out) {
    __shared__ float Ws[64 * 40];
    __shared__ float bs[40];
    int t = threadIdx.x;
    for (int idx = t; idx < 64 * 40; idx += 256) Ws[idx] = W[idx];
    if (t < 40) bs[t] = b[t];
    __syncthreads();
    int wid = blockIdx.x * (blockDim.x >> 6) + (t >> 6);
    int lane = t & 63;
    if (wid >= N_NODES) return;
    float hv = h[(size_t)wid * 64 + lane];
    float acc = (lane < 40) ? bs[lane] : 0.f;
#pragma unroll
    for (int k = 0; k < 64; ++k) {
        float hk = __shfl(hv, k);
        float wv = (lane < 40) ? Ws[k * 40 + lane] : 0.f;
        acc += hk * wv;
    }
    if (lane < 40) out[(size_t)wid * 40 + lane] = acc;
}

// ---------------- launcher ----------------

extern "C" void kernel_launch(void* const* d_in, const int* in_sizes, int n_in,
                              void* d_out, int out_size, void* d_ws, size_t ws_size,
                              hipStream_t stream) {
    const float* x        = (const float*)d_in[0];
    const int* ei         = (const int*)d_in[1];   // harness passes integers as int32
    const float* W_in     = (const float*)d_in[2];
    const float* b_in     = (const float*)d_in[3];
    const float* W_conv   = (const float*)d_in[4];
    const float* att_src  = (const float*)d_in[5];
    const float* att_dst  = (const float*)d_in[6];
    const float* b_conv   = (const float*)d_in[7];
    const float* W_out    = (const float*)d_in[8];
    const float* b_out    = (const float*)d_in[9];
    float* out = (float*)d_out;

    char* w = (char*)d_ws;
    float*  hA   = (float*)w;  w += (size_t)N_NODES * 64 * 4;   // 25.6 MB
    float*  h2f  = (float*)w;  w += (size_t)N_NODES * 64 * 4;   // 25.6 MB
    __half* h2h  = (__half*)w; w += (size_t)N_NODES * 64 * 2;   // 12.8 MB
    float*  as_  = (float*)w;  w += (size_t)N_NODES * 4;
    float*  ad_  = (float*)w;  w += (size_t)N_NODES * 4;
    int*    rp   = (int*)w;    w += 400016;                     // N+1 ints, padded
    int*    deg  = (int*)w;    w += (size_t)N_NODES * 4;        // reused as cursor
    int*    bsum = (int*)w;    w += 4096;
    int*    col  = (int*)w;    w += (size_t)N_EDGES * 4;

    // CSR build (dst-grouped; self-loops handled analytically in aggregation)
    hipMemsetAsync(deg, 0, (size_t)N_NODES * 4, stream);
    histo_kernel<<<2048, 256, 0, stream>>>(ei, deg);
    int nsb = (N_NODES + 1023) / 1024;  // 98
    scan_block_kernel<<<nsb, 1024, 0, stream>>>(deg, rp, bsum, N_NODES);
    scan_partials_kernel<<<1, 1024, 0, stream>>>(bsum, nsb);
    fixup_kernel<<<(N_NODES + 256) / 256, 256, 0, stream>>>(rp, bsum, deg, N_NODES);
    fill_kernel<<<2048, 256, 0, stream>>>(ei, deg, col);

    // input transform
    gemm_rt<<<(N_NODES + 63) / 64, 256, 0, stream>>>(x, W_in, b_in, hA, N_NODES, NFEAT);

    for (int l = 0; l < N_LAYERS; ++l) {
        gemm_rt<<<(N_NODES + 63) / 64, 256, 0, stream>>>(hA, W_conv + (size_t)l * 64 * 64,
                                                         nullptr, h2f, N_NODES, 64);
        att_dots_kernel<<<N_NODES / 4, 256, 0, stream>>>(h2f, att_src + l * 64,
                                                         att_dst + l * 64, as_, ad_, h2h);
        gat_aggregate<<<N_NODES / 4, 256, 0, stream>>>(rp, col, h2h, h2f, as_, ad_,
                                                       b_conv + l * 64, hA);
    }

    out_gemm<<<N_NODES / 4, 256, 0, stream>>>(hA, W_out, b_out, out);
}